// Round 10
// baseline (130.428 us; speedup 1.0000x reference)
//
#include <hip/hip_runtime.h>
#include <math.h>

#define BB 16
#define TT 2048
#define FF 512

#define WT_BLOCKS   8192     // 4 rows (waves) per block
#define ZERO_BLOCKS 1024     // rows j in [1024,2048): always zero (counts <= 1024), 16 rows/block
#define ACTIVE_BLOCKS 4096   // pool rows j<1024, 1 wave/row
#define MASK_BLOCKS 32

typedef float v4f __attribute__((ext_vector_type(4)));

// K1: wt[b,t] = sigmoid(dot(x[b,t,:], w) + bias), one wave per row (blocks < WT_BLOCKS);
//     plus the guaranteed-zero output region j>=1024 (blocks >= WT_BLOCKS), which
//     depends on nothing and overlaps NT stores with wt's read-bound phase.
__global__ __launch_bounds__(256) void wt_zero_kernel(const float* __restrict__ x,
                                                      const float* __restrict__ w,
                                                      const float* __restrict__ bias,
                                                      float* __restrict__ wt,
                                                      float* __restrict__ out) {
    int blk = blockIdx.x;
    int tid = threadIdx.x;
    if (blk >= WT_BLOCKS) {
        // ---- zero region: rows j in [1024, 2048), 16 rows per block ----
        int zb = blk - WT_BLOCKS;            // [0, 1024)
        int b  = zb >> 6;                    // 64 blocks per batch
        int j0 = 1024 + (zb & 63) * 16;
        float* base = out + ((size_t)(b * TT + j0) * FF);
        v4f zero = (v4f)(0.f);
        v4f* dst = (v4f*)base + tid * 2;
        __builtin_nontemporal_store(zero, dst);
        __builtin_nontemporal_store(zero, dst + 1);
        return;
    }
    int gid  = blk * 256 + tid;
    int row  = gid >> 6;    // [0, B*T)
    int lane = gid & 63;
    const float* xr = x + (size_t)row * FF + lane * 8;
    const float* wr = w + lane * 8;
    float4 a0 = *(const float4*)xr;
    float4 a1 = *(const float4*)(xr + 4);
    float4 w0 = *(const float4*)wr;
    float4 w1 = *(const float4*)(wr + 4);
    float s = a0.x * w0.x + a0.y * w0.y + a0.z * w0.z + a0.w * w0.w
            + a1.x * w1.x + a1.y * w1.y + a1.z * w1.z + a1.w * w1.w;
#pragma unroll
    for (int off = 32; off > 0; off >>= 1) s += __shfl_xor(s, off, 64);
    if (lane == 0) {
        float z = s + bias[0];
        wt[row] = 1.0f / (1.0f + expf(-z));
    }
}

// K2: one WAVE per batch. Valley detect + wave-scan compaction, no barriers.
__global__ __launch_bounds__(64) void seg_kernel(const float* __restrict__ wt,
                                                 int* __restrict__ starts,
                                                 int* __restrict__ ends,
                                                 int* __restrict__ counts) {
    int b    = blockIdx.x;
    int lane = threadIdx.x;              // 0..63, 32 consecutive positions each
    const float* wrow = wt + b * TT;
    float v[32];
    const float4* p = (const float4*)(wrow + lane * 32);
#pragma unroll
    for (int k = 0; k < 8; ++k) {
        float4 f = p[k];
        v[4*k] = f.x; v[4*k+1] = f.y; v[4*k+2] = f.z; v[4*k+3] = f.w;
    }
    float left  = __shfl_up(v[31], 1, 64);
    float right = __shfl_down(v[0], 1, 64);
    unsigned int flags = 0;
#pragma unroll
    for (int k = 0; k < 32; ++k) {
        int t = lane * 32 + k;
        float prev = (k == 0)  ? left  : v[k - 1];
        float next = (k == 31) ? right : v[k + 1];
        bool val = (t > 0) && (t < TT - 1) && (v[k] < prev) && (v[k] < next);
        if (val) flags |= (1u << k);
    }
    int cnt = __popc(flags);
    int inc = cnt;
#pragma unroll
    for (int off = 1; off < 64; off <<= 1) {
        int y = __shfl_up(inc, off, 64);
        if (lane >= off) inc += y;
    }
    int total = __shfl(inc, 63, 64);
    int r = inc - cnt;
    int* sb = starts + b * TT;
    int* eb = ends + b * TT;
    unsigned int f = flags;
    while (f) {
        int k = __ffs(f) - 1;
        f &= f - 1;
        int t = lane * 32 + k;
        sb[r + 1] = t;
        eb[r] = t + 2;                   // t <= 2046 -> t+2 <= TT
        ++r;
    }
    if (lane == 0) {
        sb[0] = 0;
        eb[total] = TT;
        counts[b] = total + 1;
    }
}

// K3: active pool (rows j<1024, 1 wave/row, unroll-8 clamped gather) + mask.
__global__ __launch_bounds__(256) void pool_kernel(const float* __restrict__ x,
                                                   const float* __restrict__ wt,
                                                   const int* __restrict__ starts,
                                                   const int* __restrict__ ends,
                                                   const int* __restrict__ counts,
                                                   const int* __restrict__ seq_len,
                                                   float* __restrict__ out,
                                                   float* __restrict__ mask_out) {
    int blk = blockIdx.x;
    int tid = threadIdx.x;

    if (blk >= ACTIVE_BLOCKS) {
        // ---- mask ----
        int idx = (blk - ACTIVE_BLOCKS) * 256 + tid;  // [0, 8192)
        int maxc = 0;
#pragma unroll
        for (int i = 0; i < BB; ++i) maxc = max(maxc, counts[i]);
        float len0 = (float)min(seq_len[0], TT);
#pragma unroll
        for (int r = 0; r < 4; ++r) {
            int i = idx + r * 8192;
            int b = i >> 11, t = i & (TT - 1);
            int nl = (int)((float)min(seq_len[b], TT) / len0 * (float)maxc);
            mask_out[i] = (t < nl) ? 1.0f : 0.0f;
        }
        return;
    }

    // ---- active pool: 4 waves/block, 1 wave/row, j in [0,1024) ----
    int b    = blk >> 8;                  // 256 blocks per batch
    int wv   = tid >> 6;
    int lane = tid & 63;
    int j    = (blk & 255) * 4 + wv;
    int row  = b * TT + j;
    float* orow = out + (size_t)row * FF + lane * 8;

    v4f acc0 = (v4f)(0.f);
    v4f acc1 = (v4f)(0.f);
    if (j < counts[b]) {
        int s = __builtin_amdgcn_readfirstlane(starts[row]);
        int e = __builtin_amdgcn_readfirstlane(ends[row]);
        const float* xb   = x + (size_t)b * TT * FF + lane * 8;
        const float* wrow = wt + b * TT;
        float den = 0.f;
        for (int t = s; t < e; t += 8) {
            int   ii[8];
            float ww[8];
#pragma unroll
            for (int k = 0; k < 8; ++k) {
                int tt = t + k;
                bool in = (tt < e);
                ii[k] = in ? tt : t;
                ww[k] = in ? wrow[ii[k]] : 0.f;
            }
#pragma unroll
            for (int k = 0; k < 8; ++k) {
                const v4f* p = (const v4f*)(xb + (size_t)ii[k] * FF);
                v4f v0 = p[0], v1 = p[1];
                acc0 += ww[k] * v0;
                acc1 += ww[k] * v1;
                den  += ww[k];
            }
        }
        float inv = 1.0f / fmaxf(den, 1e-6f);
        acc0 *= inv; acc1 *= inv;
    }
    __builtin_nontemporal_store(acc0, (v4f*)orow);
    __builtin_nontemporal_store(acc1, (v4f*)(orow + 4));
}

extern "C" void kernel_launch(void* const* d_in, const int* in_sizes, int n_in,
                              void* d_out, int out_size, void* d_ws, size_t ws_size,
                              hipStream_t stream) {
    const float* x       = (const float*)d_in[0];
    const float* w_aggr  = (const float*)d_in[1];
    const float* b_aggr  = (const float*)d_in[2];
    const int*   seq_len = (const int*)d_in[3];

    float* pooled = (float*)d_out;
    float* mask   = (float*)d_out + (size_t)BB * TT * FF;

    float* wt    = (float*)d_ws;
    int* starts  = (int*)((char*)d_ws + (size_t)BB * TT * 4);
    int* ends    = starts + BB * TT;
    int* counts  = ends + BB * TT;

    wt_zero_kernel<<<WT_BLOCKS + ZERO_BLOCKS, 256, 0, stream>>>(x, w_aggr, b_aggr, wt, pooled);
    seg_kernel<<<BB, 64, 0, stream>>>(wt, starts, ends, counts);
    pool_kernel<<<ACTIVE_BLOCKS + MASK_BLOCKS, 256, 0, stream>>>(
        x, wt, starts, ends, counts, seq_len, pooled, mask);
}